// Round 6
// baseline (204.997 us; speedup 1.0000x reference)
//
#include <hip/hip_runtime.h>
#include <math.h>

#define TT 8192
#define HH 5120
#define EE 160
#define NGRP 8
#define GSZ 20
#define TOPKG 3
#define TOPK 6
#define RSCALE 16.0f

typedef __attribute__((ext_vector_type(8))) short bf16x8;
typedef __attribute__((ext_vector_type(4))) float f32x4;

#define BW_ELEMS ((size_t)160 * 10 * 64 * 8)   // 819200 ushorts per B copy

__device__ __forceinline__ ushort f2bf(float f) {
    uint32_t u = __float_as_uint(f);
    u += 0x7fff + ((u >> 16) & 1);   // RNE
    return (ushort)(u >> 16);
}
__device__ __forceinline__ float bf2f(ushort h) {
    return __uint_as_float(((uint32_t)h) << 16);
}

// ---------------- Kernel 1: B [160][5120] fp32 -> bf16 hi+lo fragment-linear ----
// layout per copy: [kt 0..159][et 0..9][lane 0..63][8 bf16]; lane&15 = expert,
// lane>>4 = k-octet -> mfma_f32_16x16x32_bf16 B-operand frag. Lo copy at +BW_ELEMS.
__global__ __launch_bounds__(256) void prep_b(const float* __restrict__ B,
                                              ushort* __restrict__ Bw) {
    int gid = blockIdx.x * 256 + threadIdx.x;        // < 102400
    int lane = gid & 63;
    int et   = (gid >> 6) % 10;
    int kt   = gid / 640;
    int e = et * 16 + (lane & 15);
    int c = kt * 32 + (lane >> 4) * 8;
    const float* src = B + (size_t)e * HH + c;
    uint4 vh, vl;
    uint32_t hw[8], lw[8];
    #pragma unroll
    for (int j = 0; j < 8; j++) {
        float f = src[j];
        ushort h = f2bf(f);
        float r = f - bf2f(h);
        hw[j] = h;
        lw[j] = f2bf(r);
    }
    vh.x = hw[0] | (hw[1] << 16); vh.y = hw[2] | (hw[3] << 16);
    vh.z = hw[4] | (hw[5] << 16); vh.w = hw[6] | (hw[7] << 16);
    vl.x = lw[0] | (lw[1] << 16); vl.y = lw[2] | (lw[3] << 16);
    vl.z = lw[4] | (lw[5] << 16); vl.w = lw[6] | (lw[7] << 16);
    *reinterpret_cast<uint4*>(Bw + (size_t)gid * 8) = vh;
    *reinterpret_cast<uint4*>(Bw + BW_ELEMS + (size_t)gid * 8) = vl;
}

// ---------------- Kernel 2: fused MFMA gemm + softmax + group-topk routing ------
#define BM 32
#define BK 256
#define NT (HH / BK)     // 20
#define PS (EE + 1)      // 161

__device__ __forceinline__ void cvt_write(char* AH, char* AL, int ws0, int ws1,
                                          f32x4 a, f32x4 b, f32x4 c, f32x4 d) {
    float fv[16] = {a[0], a[1], a[2], a[3], b[0], b[1], b[2], b[3],
                    c[0], c[1], c[2], c[3], d[0], d[1], d[2], d[3]};
    uint32_t hp[8], lp[8];
    #pragma unroll
    for (int j = 0; j < 8; j++) {
        ushort h0 = f2bf(fv[2*j]), h1 = f2bf(fv[2*j+1]);
        float  l0 = fv[2*j]   - bf2f(h0);
        float  l1 = fv[2*j+1] - bf2f(h1);
        hp[j] = (uint32_t)h0 | ((uint32_t)h1 << 16);
        lp[j] = (uint32_t)f2bf(l0) | ((uint32_t)f2bf(l1) << 16);
    }
    *(uint4*)(AH + ws0) = make_uint4(hp[0], hp[1], hp[2], hp[3]);
    *(uint4*)(AH + ws1) = make_uint4(hp[4], hp[5], hp[6], hp[7]);
    *(uint4*)(AL + ws0) = make_uint4(lp[0], lp[1], lp[2], lp[3]);
    *(uint4*)(AL + ws1) = make_uint4(lp[4], lp[5], lp[6], lp[7]);
}

// load one tile's B slice (hi+lo) for this wave into a named register set
#define LOADB(SETH, SETL, T) {                                                     \
    const ushort* bt_  = Bw + ((size_t)(((T) * 8 + w) * 10) * 64 + (size_t)l) * 8; \
    const ushort* btl_ = bt_ + BW_ELEMS;                                           \
    _Pragma("unroll")                                                              \
    for (int et_ = 0; et_ < 10; ++et_) {                                           \
        SETH[et_] = *(const bf16x8*)(bt_  + et_ * 512);                            \
        SETL[et_] = *(const bf16x8*)(btl_ + et_ * 512);                            \
    } }

// one pipeline step: compute staggered tile (t0+I)%NT from buf BUFSEL using CUR
// register set; prefetch tile (t0+I+1)%NT into NXT set + other LDS buffer.
#define STEP(I, BUFSEL, CURH, CURL, NXTH, NXTL) {                                  \
    const bool more_ = (I) + 1 < NT;                                               \
    int tn_ = t0 + (I) + 1; if (tn_ >= NT) tn_ -= NT;                              \
    f32x4 n0_ = {0,0,0,0}, n1_ = {0,0,0,0}, n2_ = {0,0,0,0}, n3_ = {0,0,0,0};      \
    if (more_) {                                                                   \
        const f32x4* p_ = (const f32x4*)(ap + (size_t)tn_ * BK);                   \
        n0_ = p_[0]; n1_ = p_[1]; n2_ = p_[2]; n3_ = p_[3];                        \
        LOADB(NXTH, NXTL, tn_);                                                    \
    }                                                                              \
    asm volatile("s_waitcnt lgkmcnt(0)" ::: "memory");                             \
    __builtin_amdgcn_sched_barrier(0);                                             \
    __builtin_amdgcn_s_barrier();                                                  \
    __builtin_amdgcn_sched_barrier(0);                                             \
    char* AHc_ = lds + (size_t)(BUFSEL) * 32768;                                   \
    char* ALc_ = AHc_ + 16384;                                                     \
    bf16x8 ah0_ = *(bf16x8*)(AHc_ + ra0);                                          \
    bf16x8 ah1_ = *(bf16x8*)(AHc_ + ra1);                                          \
    bf16x8 al0_ = *(bf16x8*)(ALc_ + ra0);                                          \
    bf16x8 al1_ = *(bf16x8*)(ALc_ + ra1);                                          \
    _Pragma("unroll")                                                              \
    for (int et_ = 0; et_ < 10; ++et_) {                                           \
        acc[0][et_] = __builtin_amdgcn_mfma_f32_16x16x32_bf16(ah0_, CURH[et_], acc[0][et_], 0, 0, 0); \
        acc[1][et_] = __builtin_amdgcn_mfma_f32_16x16x32_bf16(ah1_, CURH[et_], acc[1][et_], 0, 0, 0); \
        acc[0][et_] = __builtin_amdgcn_mfma_f32_16x16x32_bf16(al0_, CURH[et_], acc[0][et_], 0, 0, 0); \
        acc[1][et_] = __builtin_amdgcn_mfma_f32_16x16x32_bf16(al1_, CURH[et_], acc[1][et_], 0, 0, 0); \
        acc[0][et_] = __builtin_amdgcn_mfma_f32_16x16x32_bf16(ah0_, CURL[et_], acc[0][et_], 0, 0, 0); \
        acc[1][et_] = __builtin_amdgcn_mfma_f32_16x16x32_bf16(ah1_, CURL[et_], acc[1][et_], 0, 0, 0); \
    }                                                                              \
    __builtin_amdgcn_sched_barrier(0);                                             \
    if (more_) {                                                                   \
        char* AHn_ = lds + (size_t)(1 - (BUFSEL)) * 32768;                         \
        cvt_write(AHn_, AHn_ + 16384, ws0, ws1, n0_, n1_, n2_, n3_);               \
    } }

__global__ __launch_bounds__(512, 2) void moe_mfma(const float* __restrict__ A,
                                                   const ushort* __restrict__ Bw,
                                                   float* __restrict__ out) {
    // LDS: buf0 [AH 16K | AL 16K] at 0, buf1 at 32K. Sc (32x161 f32, 20608B)
    // aliases buf0 after the GEMM loop. Total 64KB.
    __shared__ char lds[65536];

    const int tid = threadIdx.x;
    const int w = tid >> 6, l = tid & 63;
    const int bm0 = blockIdx.x * BM;
    // stagger K-tile order per block: kills the 256-blocks-on-one-B-tile
    // bank hotspot (7 coprime to 20 spreads neighbor blocks far apart)
    const int t0 = (blockIdx.x * 7) % NT;

    // ---- A staging map: thread -> 16 consecutive fp32 of one row
    const int sr   = tid >> 4;            // 0..31 (token row)
    const int scol = (tid & 15) << 4;     // 0..240
    const int sw   = scol >> 5;           // owner wave (K32 slice) 0..7
    const int sg2  = (scol & 31) >> 3;    // 0 or 2 (k-octet group)
    const int r4   = sr & 15;
    const int smt  = sr >> 4;
    const int wb   = (sw * 2 + smt) * 1024;
    const int ws0  = wb + ((sg2 * 16 + r4) ^ sw) * 16;        // XOR swizzle
    const int ws1  = wb + (((sg2 + 1) * 16 + r4) ^ sw) * 16;

    const float* ap = A + (size_t)(bm0 + sr) * HH + scol;

    // ---- A-frag read offsets (lane-linear 16B, same XOR on read side)
    const int rslot = (l ^ (w & 7)) * 16;
    const int ra0 = (w * 2 + 0) * 1024 + rslot;
    const int ra1 = (w * 2 + 1) * 1024 + rslot;

    f32x4 acc[2][10];
    #pragma unroll
    for (int mt = 0; mt < 2; mt++)
        #pragma unroll
        for (int et = 0; et < 10; et++) acc[mt][et] = (f32x4){0.f, 0.f, 0.f, 0.f};

    bf16x8 bhA[10], blA[10], bhB[10], blB[10];

    // ---- prologue: tile t0 -> buf0 + its B slice -> set A
    {
        const f32x4* p = (const f32x4*)(ap + (size_t)t0 * BK);
        cvt_write(lds, lds + 16384, ws0, ws1, p[0], p[1], p[2], p[3]);
        LOADB(bhA, blA, t0);
    }

    #pragma unroll 1
    for (int i = 0; i < NT; i += 2) {
        STEP(i,     0, bhA, blA, bhB, blB);
        STEP(i + 1, 1, bhB, blB, bhA, blA);
    }

    // ---- Sc aliases buf0 (last tile was read from buf1; no overlap)
    float* Sc = (float*)lds;
    __syncthreads();
    for (int i = tid; i < BM * PS; i += 512) Sc[i] = 0.f;
    __syncthreads();

    // ---- cross-wave K-reduction into Sc (LDS f32 atomics; static acc indexing)
    const int rrow = (l >> 4) * 4;
    const int rcol = l & 15;
    #pragma unroll
    for (int mt = 0; mt < 2; mt++)
        #pragma unroll
        for (int et = 0; et < 10; et++)
            #pragma unroll
            for (int j = 0; j < 4; j++)
                atomicAdd(&Sc[(mt * 16 + rrow + j) * PS + et * 16 + rcol], acc[mt][et][j]);
    __syncthreads();

    // ---- routing: one wave per token, 4 tokens per wave (validated R0/R2)
    for (int it = 0; it < 4; ++it) {
        const int r = w * 4 + it;
        float s0 = Sc[r * PS + l];
        float s1 = Sc[r * PS + 64 + l];
        float s2 = (l < 32) ? Sc[r * PS + 128 + l] : -INFINITY;

        float m = fmaxf(s0, fmaxf(s1, s2));
        #pragma unroll
        for (int off = 32; off >= 1; off >>= 1) m = fmaxf(m, __shfl_xor(m, off, 64));
        float p0 = expf(s0 - m);
        float p1 = expf(s1 - m);
        float p2 = (l < 32) ? expf(s2 - m) : 0.f;
        float sum = p0 + p1 + p2;
        #pragma unroll
        for (int off = 32; off >= 1; off >>= 1) sum += __shfl_xor(sum, off, 64);
        float inv = 1.0f / sum;
        p0 *= inv; p1 *= inv; p2 *= inv;

        const int g0 = l / GSZ;
        const int g1 = (l + 64) / GSZ;
        const int g2 = (l + 128) / GSZ;

        float gmax[NGRP];
        #pragma unroll
        for (int g = 0; g < NGRP; g++) {
            float v = -1.f;
            if (g0 == g) v = p0;
            if (g1 == g) v = fmaxf(v, p1);
            if (l < 32 && g2 == g) v = fmaxf(v, p2);
            #pragma unroll
            for (int off = 32; off >= 1; off >>= 1) v = fmaxf(v, __shfl_xor(v, off, 64));
            gmax[g] = v;
        }

        int selmask = 0;
        #pragma unroll
        for (int s = 0; s < TOPKG; s++) {
            float best = -2.f; int bg = 0;
            #pragma unroll
            for (int g = 0; g < NGRP; g++)
                if (!((selmask >> g) & 1) && gmax[g] > best) { best = gmax[g]; bg = g; }
            selmask |= 1 << bg;
        }

        float m0 = ((selmask >> g0) & 1) ? p0 : 0.f;
        float m1 = ((selmask >> g1) & 1) ? p1 : 0.f;
        float m2 = (l < 32) ? (((selmask >> g2) & 1) ? p2 : 0.f) : -1.f;

        #pragma unroll
        for (int s = 0; s < TOPK; s++) {
            float v = fmaxf(m0, fmaxf(m1, m2));
            #pragma unroll
            for (int off = 32; off >= 1; off >>= 1) v = fmaxf(v, __shfl_xor(v, off, 64));
            int idx = 0x7fffffff;
            if (m0 == v) idx = l;
            if (m1 == v) idx = min(idx, l + 64);
            if (l < 32 && m2 == v) idx = min(idx, l + 128);
            #pragma unroll
            for (int off = 32; off >= 1; off >>= 1) idx = min(idx, __shfl_xor(idx, off, 64));
            if (idx == l)            m0 = -1.f;
            else if (idx == l + 64)  m1 = -1.f;
            else if (l < 32 && idx == l + 128) m2 = -1.f;
            if (l == 0) out[(size_t)(bm0 + r) * TOPK + s] = v * RSCALE;
        }
    }
}

// ---------------- Fallback (R0 fp32 kernel, used only if ws too small) ----------
#define FBM 32
#define FBK 64
#define FPK (FBK + 1)

__global__ __launch_bounds__(256) void moe_gate_fused(const float* __restrict__ Ag,
                                                      const float* __restrict__ Bg,
                                                      float* __restrict__ out) {
    __shared__ float smem[FBM * FPK + EE * FPK];
    float* As = smem;
    float* Bs = smem + FBM * FPK;
    float* Scf = smem + FBM * FPK;

    const int t = threadIdx.x;
    const int bm0 = blockIdx.x * FBM;
    const int tm = t & 7;
    const int te = t >> 3;
    float acc[4][5];
    #pragma unroll
    for (int i = 0; i < 4; i++)
        #pragma unroll
        for (int j = 0; j < 5; j++) acc[i][j] = 0.f;
    const int lr = t >> 4;
    const int lc = (t & 15) << 2;
    const int aBase = (4 * tm) * FPK;
    const int bBase = (5 * te) * FPK;

    for (int k0 = 0; k0 < HH; k0 += FBK) {
        __syncthreads();
        {
            float4 v0 = *reinterpret_cast<const float4*>(Ag + (size_t)(bm0 + lr) * HH + k0 + lc);
            float4 v1 = *reinterpret_cast<const float4*>(Ag + (size_t)(bm0 + lr + 16) * HH + k0 + lc);
            As[lr * FPK + lc + 0] = v0.x; As[lr * FPK + lc + 1] = v0.y;
            As[lr * FPK + lc + 2] = v0.z; As[lr * FPK + lc + 3] = v0.w;
            As[(lr + 16) * FPK + lc + 0] = v1.x; As[(lr + 16) * FPK + lc + 1] = v1.y;
            As[(lr + 16) * FPK + lc + 2] = v1.z; As[(lr + 16) * FPK + lc + 3] = v1.w;
        }
        #pragma unroll
        for (int i = 0; i < 10; i++) {
            int e = lr + 16 * i;
            float4 v = *reinterpret_cast<const float4*>(Bg + (size_t)e * HH + k0 + lc);
            Bs[e * FPK + lc + 0] = v.x; Bs[e * FPK + lc + 1] = v.y;
            Bs[e * FPK + lc + 2] = v.z; Bs[e * FPK + lc + 3] = v.w;
        }
        __syncthreads();
        #pragma unroll 4
        for (int k = 0; k < FBK; k++) {
            float a0 = As[aBase + 0 * FPK + k], a1 = As[aBase + 1 * FPK + k];
            float a2 = As[aBase + 2 * FPK + k], a3 = As[aBase + 3 * FPK + k];
            float b0 = Bs[bBase + 0 * FPK + k], b1 = Bs[bBase + 1 * FPK + k];
            float b2 = Bs[bBase + 2 * FPK + k], b3 = Bs[bBase + 3 * FPK + k];
            float b4 = Bs[bBase + 4 * FPK + k];
            acc[0][0] = fmaf(a0, b0, acc[0][0]); acc[0][1] = fmaf(a0, b1, acc[0][1]);
            acc[0][2] = fmaf(a0, b2, acc[0][2]); acc[0][3] = fmaf(a0, b3, acc[0][3]);
            acc[0][4] = fmaf(a0, b4, acc[0][4]);
            acc[1][0] = fmaf(a1, b0, acc[1][0]); acc[1][1] = fmaf(a1, b1, acc[1][1]);
            acc[1][2] = fmaf(a1, b2, acc[1][2]); acc[1][3] = fmaf(a1, b3, acc[1][3]);
            acc[1][4] = fmaf(a1, b4, acc[1][4]);
            acc[2][0] = fmaf(a2, b0, acc[2][0]); acc[2][1] = fmaf(a2, b1, acc[2][1]);
            acc[2][2] = fmaf(a2, b2, acc[2][2]); acc[2][3] = fmaf(a2, b3, acc[2][3]);
            acc[2][4] = fmaf(a2, b4, acc[2][4]);
            acc[3][0] = fmaf(a3, b0, acc[3][0]); acc[3][1] = fmaf(a3, b1, acc[3][1]);
            acc[3][2] = fmaf(a3, b2, acc[3][2]); acc[3][3] = fmaf(a3, b3, acc[3][3]);
            acc[3][4] = fmaf(a3, b4, acc[3][4]);
        }
    }
    __syncthreads();
    #pragma unroll
    for (int i = 0; i < 4; i++)
        #pragma unroll
        for (int j = 0; j < 5; j++)
            Scf[(4 * tm + i) * PS + (5 * te + j)] = acc[i][j];
    __syncthreads();

    const int w = t >> 6;
    const int l = t & 63;
    for (int it = 0; it < 8; ++it) {
        const int r = w * 8 + it;
        float s0 = Scf[r * PS + l];
        float s1 = Scf[r * PS + 64 + l];
        float s2 = (l < 32) ? Scf[r * PS + 128 + l] : -INFINITY;
        float m = fmaxf(s0, fmaxf(s1, s2));
        #pragma unroll
        for (int off = 32; off >= 1; off >>= 1) m = fmaxf(m, __shfl_xor(m, off, 64));
        float p0 = expf(s0 - m), p1 = expf(s1 - m);
        float p2 = (l < 32) ? expf(s2 - m) : 0.f;
        float sum = p0 + p1 + p2;
        #pragma unroll
        for (int off = 32; off >= 1; off >>= 1) sum += __shfl_xor(sum, off, 64);
        float inv = 1.0f / sum;
        p0 *= inv; p1 *= inv; p2 *= inv;
        const int g0 = l / GSZ, g1 = (l + 64) / GSZ, g2 = (l + 128) / GSZ;
        float gmax[NGRP];
        #pragma unroll
        for (int g = 0; g < NGRP; g++) {
            float v = -1.f;
            if (g0 == g) v = p0;
            if (g1 == g) v = fmaxf(v, p1);
            if (l < 32 && g2 == g) v = fmaxf(v, p2);
            #pragma unroll
            for (int off = 32; off >= 1; off >>= 1) v = fmaxf(v, __shfl_xor(v, off, 64));
            gmax[g] = v;
        }
        int selmask = 0;
        #pragma unroll
        for (int s = 0; s < TOPKG; s++) {
            float best = -2.f; int bg = 0;
            #pragma unroll
            for (int g = 0; g < NGRP; g++)
                if (!((selmask >> g) & 1) && gmax[g] > best) { best = gmax[g]; bg = g; }
            selmask |= 1 << bg;
        }
        float m0 = ((selmask >> g0) & 1) ? p0 : 0.f;
        float m1 = ((selmask >> g1) & 1) ? p1 : 0.f;
        float m2 = (l < 32) ? (((selmask >> g2) & 1) ? p2 : 0.f) : -1.f;
        #pragma unroll
        for (int s = 0; s < TOPK; s++) {
            float v = fmaxf(m0, fmaxf(m1, m2));
            #pragma unroll
            for (int off = 32; off >= 1; off >>= 1) v = fmaxf(v, __shfl_xor(v, off, 64));
            int idx = 0x7fffffff;
            if (m0 == v) idx = l;
            if (m1 == v) idx = min(idx, l + 64);
            if (l < 32 && m2 == v) idx = min(idx, l + 128);
            #pragma unroll
            for (int off = 32; off >= 1; off >>= 1) idx = min(idx, __shfl_xor(idx, off, 64));
            if (idx == l)            m0 = -1.f;
            else if (idx == l + 64)  m1 = -1.f;
            else if (l < 32 && idx == l + 128) m2 = -1.f;
            if (l == 0) out[(size_t)(bm0 + r) * TOPK + s] = v * RSCALE;
        }
    }
}

extern "C" void kernel_launch(void* const* d_in, const int* in_sizes, int n_in,
                              void* d_out, int out_size, void* d_ws, size_t ws_size,
                              hipStream_t stream) {
    const float* hs = (const float*)d_in[0];   // [8192][5120] fp32
    const float* kn = (const float*)d_in[1];   // [160][5120] fp32
    float* o = (float*)d_out;                  // [8192][6] fp32

    const size_t bwBytes = 2 * BW_ELEMS * sizeof(ushort);  // 3,276,800 (hi + lo)
    if (ws_size >= bwBytes) {
        ushort* Bw = (ushort*)d_ws;
        hipLaunchKernelGGL(prep_b, dim3(400), dim3(256), 0, stream, kn, Bw);
        hipLaunchKernelGGL(moe_mfma, dim3(TT / BM), dim3(512), 0, stream, hs, Bw, o);
    } else {
        hipLaunchKernelGGL(moe_gate_fused, dim3(TT / FBM), dim3(256), 0, stream, hs, kn, o);
    }
}

// Round 7
// 153.466 us; speedup vs baseline: 1.3358x; 1.3358x over previous
//
#include <hip/hip_runtime.h>
#include <math.h>

#define TT 8192
#define HH 5120
#define EE 160
#define NGRP 8
#define GSZ 20
#define TOPKG 3
#define TOPK 6
#define RSCALE 16.0f

typedef __attribute__((ext_vector_type(8))) short bf16x8;
typedef __attribute__((ext_vector_type(4))) float f32x4;

#define BW_ELEMS ((size_t)160 * 10 * 64 * 8)   // 819200 ushorts per B copy

__device__ __forceinline__ ushort f2bf(float f) {
    uint32_t u = __float_as_uint(f);
    u += 0x7fff + ((u >> 16) & 1);   // RNE
    return (ushort)(u >> 16);
}
__device__ __forceinline__ float bf2f(ushort h) {
    return __uint_as_float(((uint32_t)h) << 16);
}

// ---------------- Kernel 1: B [160][5120] fp32 -> bf16 hi+lo fragment-linear ----
// layout per copy: [kt 0..159][et 0..9][lane 0..63][8 bf16]; lane&15 = expert,
// lane>>4 = k-octet -> mfma_f32_16x16x32_bf16 B-operand frag. Lo copy at +BW_ELEMS.
__global__ __launch_bounds__(256) void prep_b(const float* __restrict__ B,
                                              ushort* __restrict__ Bw) {
    int gid = blockIdx.x * 256 + threadIdx.x;        // < 102400
    int lane = gid & 63;
    int et   = (gid >> 6) % 10;
    int kt   = gid / 640;
    int e = et * 16 + (lane & 15);
    int c = kt * 32 + (lane >> 4) * 8;
    const float* src = B + (size_t)e * HH + c;
    uint4 vh, vl;
    uint32_t hw[8], lw[8];
    #pragma unroll
    for (int j = 0; j < 8; j++) {
        float f = src[j];
        ushort h = f2bf(f);
        float r = f - bf2f(h);
        hw[j] = h;
        lw[j] = f2bf(r);
    }
    vh.x = hw[0] | (hw[1] << 16); vh.y = hw[2] | (hw[3] << 16);
    vh.z = hw[4] | (hw[5] << 16); vh.w = hw[6] | (hw[7] << 16);
    vl.x = lw[0] | (lw[1] << 16); vl.y = lw[2] | (lw[3] << 16);
    vl.z = lw[4] | (lw[5] << 16); vl.w = lw[6] | (lw[7] << 16);
    *reinterpret_cast<uint4*>(Bw + (size_t)gid * 8) = vh;
    *reinterpret_cast<uint4*>(Bw + BW_ELEMS + (size_t)gid * 8) = vl;
}

// ---------------- Kernel 2: A-in-register MFMA gemm + softmax + routing --------
// BM=16 tokens/block, 8 waves each own K=640 (20 K32 steps). No LDS in K-loop:
// each lane loads its A-fragment (8 consecutive fp32 of row l&15) from global,
// splits hi/lo in registers. Cross-wave K-reduce via LDS atomics (validated).
#define BM 16
#define KW 640            // K per wave
#define NS (KW / 32)      // 20 steps
#define PS (EE + 1)       // 161

__global__ __launch_bounds__(512, 4) void moe_mfma(const float* __restrict__ A,
                                                   const ushort* __restrict__ Bw,
                                                   float* __restrict__ out) {
    __shared__ float Sc[BM * PS];    // 16 x 161 f32 = 10304 B

    const int tid = threadIdx.x;
    const int w = tid >> 6, l = tid & 63;
    const int bm0 = blockIdx.x * BM;
    const int row  = l & 15;         // token row within tile (A-frag + C col idx)
    const int koct = l >> 4;         // k-octet within K32 slice

    f32x4 acc[10];
    #pragma unroll
    for (int et = 0; et < 10; et++) acc[et] = (f32x4){0.f, 0.f, 0.f, 0.f};

    // wave-private A pointer: row (bm0+row), cols w*640 + koct*8 + [0..8)
    const float* apw = A + (size_t)(bm0 + row) * HH + w * KW + koct * 8;

    #pragma unroll 1
    for (int s = 0; s < NS; ++s) {
        // ---- A fragment: 8 consecutive fp32 -> bf16 hi/lo in registers
        const f32x4* p = (const f32x4*)(apw + s * 32);
        f32x4 a0 = p[0], a1 = p[1];
        float fv[8] = {a0[0], a0[1], a0[2], a0[3], a1[0], a1[1], a1[2], a1[3]};
        union { uint32_t u[4]; bf16x8 v; } uh, ul;
        #pragma unroll
        for (int j = 0; j < 4; j++) {
            ushort h0 = f2bf(fv[2*j]), h1 = f2bf(fv[2*j+1]);
            float  r0 = fv[2*j]   - bf2f(h0);
            float  r1 = fv[2*j+1] - bf2f(h1);
            uh.u[j] = (uint32_t)h0 | ((uint32_t)h1 << 16);
            ul.u[j] = (uint32_t)f2bf(r0) | ((uint32_t)f2bf(r1) << 16);
        }
        bf16x8 ah = uh.v, al = ul.v;

        // ---- B fragments for k-tile (w*20 + s), all 10 expert tiles
        const ushort* bt = Bw + ((size_t)((w * NS + s) * 10) * 64 + (size_t)l) * 8;
        #pragma unroll
        for (int et = 0; et < 10; ++et) {
            bf16x8 bh = *(const bf16x8*)(bt + et * 512);
            bf16x8 bl = *(const bf16x8*)(bt + BW_ELEMS + et * 512);
            acc[et] = __builtin_amdgcn_mfma_f32_16x16x32_bf16(ah, bh, acc[et], 0, 0, 0);
            acc[et] = __builtin_amdgcn_mfma_f32_16x16x32_bf16(al, bh, acc[et], 0, 0, 0);
            acc[et] = __builtin_amdgcn_mfma_f32_16x16x32_bf16(ah, bl, acc[et], 0, 0, 0);
        }
    }

    // ---- cross-wave K-reduction into Sc (LDS f32 atomics; static indexing)
    for (int i = tid; i < BM * PS; i += 512) Sc[i] = 0.f;
    __syncthreads();
    const int rrow = koct * 4;       // C row base = (lane>>4)*4
    const int rcol = row;            // C col = lane&15
    #pragma unroll
    for (int et = 0; et < 10; et++)
        #pragma unroll
        for (int j = 0; j < 4; j++)
            atomicAdd(&Sc[(rrow + j) * PS + et * 16 + rcol], acc[et][j]);
    __syncthreads();

    // ---- routing: one wave per token, 2 tokens per wave (validated R0/R2)
    for (int it = 0; it < 2; ++it) {
        const int r = w * 2 + it;
        float s0 = Sc[r * PS + l];
        float s1 = Sc[r * PS + 64 + l];
        float s2 = (l < 32) ? Sc[r * PS + 128 + l] : -INFINITY;

        float m = fmaxf(s0, fmaxf(s1, s2));
        #pragma unroll
        for (int off = 32; off >= 1; off >>= 1) m = fmaxf(m, __shfl_xor(m, off, 64));
        float p0 = expf(s0 - m);
        float p1 = expf(s1 - m);
        float p2 = (l < 32) ? expf(s2 - m) : 0.f;
        float sum = p0 + p1 + p2;
        #pragma unroll
        for (int off = 32; off >= 1; off >>= 1) sum += __shfl_xor(sum, off, 64);
        float inv = 1.0f / sum;
        p0 *= inv; p1 *= inv; p2 *= inv;

        const int g0 = l / GSZ;
        const int g1 = (l + 64) / GSZ;
        const int g2 = (l + 128) / GSZ;

        float gmax[NGRP];
        #pragma unroll
        for (int g = 0; g < NGRP; g++) {
            float v = -1.f;
            if (g0 == g) v = p0;
            if (g1 == g) v = fmaxf(v, p1);
            if (l < 32 && g2 == g) v = fmaxf(v, p2);
            #pragma unroll
            for (int off = 32; off >= 1; off >>= 1) v = fmaxf(v, __shfl_xor(v, off, 64));
            gmax[g] = v;
        }

        int selmask = 0;
        #pragma unroll
        for (int s = 0; s < TOPKG; s++) {
            float best = -2.f; int bg = 0;
            #pragma unroll
            for (int g = 0; g < NGRP; g++)
                if (!((selmask >> g) & 1) && gmax[g] > best) { best = gmax[g]; bg = g; }
            selmask |= 1 << bg;
        }

        float m0 = ((selmask >> g0) & 1) ? p0 : 0.f;
        float m1 = ((selmask >> g1) & 1) ? p1 : 0.f;
        float m2 = (l < 32) ? (((selmask >> g2) & 1) ? p2 : 0.f) : -1.f;

        #pragma unroll
        for (int s = 0; s < TOPK; s++) {
            float v = fmaxf(m0, fmaxf(m1, m2));
            #pragma unroll
            for (int off = 32; off >= 1; off >>= 1) v = fmaxf(v, __shfl_xor(v, off, 64));
            int idx = 0x7fffffff;
            if (m0 == v) idx = l;
            if (m1 == v) idx = min(idx, l + 64);
            if (l < 32 && m2 == v) idx = min(idx, l + 128);
            #pragma unroll
            for (int off = 32; off >= 1; off >>= 1) idx = min(idx, __shfl_xor(idx, off, 64));
            if (idx == l)            m0 = -1.f;
            else if (idx == l + 64)  m1 = -1.f;
            else if (l < 32 && idx == l + 128) m2 = -1.f;
            if (l == 0) out[(size_t)(bm0 + r) * TOPK + s] = v * RSCALE;
        }
    }
}

// ---------------- Fallback (R0 fp32 kernel, used only if ws too small) ----------
#define FBM 32
#define FBK 64
#define FPK (FBK + 1)

__global__ __launch_bounds__(256) void moe_gate_fused(const float* __restrict__ Ag,
                                                      const float* __restrict__ Bg,
                                                      float* __restrict__ out) {
    __shared__ float smem[FBM * FPK + EE * FPK];
    float* As = smem;
    float* Bs = smem + FBM * FPK;
    float* Scf = smem + FBM * FPK;

    const int t = threadIdx.x;
    const int bm0 = blockIdx.x * FBM;
    const int tm = t & 7;
    const int te = t >> 3;
    float acc[4][5];
    #pragma unroll
    for (int i = 0; i < 4; i++)
        #pragma unroll
        for (int j = 0; j < 5; j++) acc[i][j] = 0.f;
    const int lr = t >> 4;
    const int lc = (t & 15) << 2;
    const int aBase = (4 * tm) * FPK;
    const int bBase = (5 * te) * FPK;

    for (int k0 = 0; k0 < HH; k0 += FBK) {
        __syncthreads();
        {
            float4 v0 = *reinterpret_cast<const float4*>(Ag + (size_t)(bm0 + lr) * HH + k0 + lc);
            float4 v1 = *reinterpret_cast<const float4*>(Ag + (size_t)(bm0 + lr + 16) * HH + k0 + lc);
            As[lr * FPK + lc + 0] = v0.x; As[lr * FPK + lc + 1] = v0.y;
            As[lr * FPK + lc + 2] = v0.z; As[lr * FPK + lc + 3] = v0.w;
            As[(lr + 16) * FPK + lc + 0] = v1.x; As[(lr + 16) * FPK + lc + 1] = v1.y;
            As[(lr + 16) * FPK + lc + 2] = v1.z; As[(lr + 16) * FPK + lc + 3] = v1.w;
        }
        #pragma unroll
        for (int i = 0; i < 10; i++) {
            int e = lr + 16 * i;
            float4 v = *reinterpret_cast<const float4*>(Bg + (size_t)e * HH + k0 + lc);
            Bs[e * FPK + lc + 0] = v.x; Bs[e * FPK + lc + 1] = v.y;
            Bs[e * FPK + lc + 2] = v.z; Bs[e * FPK + lc + 3] = v.w;
        }
        __syncthreads();
        #pragma unroll 4
        for (int k = 0; k < FBK; k++) {
            float a0 = As[aBase + 0 * FPK + k], a1 = As[aBase + 1 * FPK + k];
            float a2 = As[aBase + 2 * FPK + k], a3 = As[aBase + 3 * FPK + k];
            float b0 = Bs[bBase + 0 * FPK + k], b1 = Bs[bBase + 1 * FPK + k];
            float b2 = Bs[bBase + 2 * FPK + k], b3 = Bs[bBase + 3 * FPK + k];
            float b4 = Bs[bBase + 4 * FPK + k];
            acc[0][0] = fmaf(a0, b0, acc[0][0]); acc[0][1] = fmaf(a0, b1, acc[0][1]);
            acc[0][2] = fmaf(a0, b2, acc[0][2]); acc[0][3] = fmaf(a0, b3, acc[0][3]);
            acc[0][4] = fmaf(a0, b4, acc[0][4]);
            acc[1][0] = fmaf(a1, b0, acc[1][0]); acc[1][1] = fmaf(a1, b1, acc[1][1]);
            acc[1][2] = fmaf(a1, b2, acc[1][2]); acc[1][3] = fmaf(a1, b3, acc[1][3]);
            acc[1][4] = fmaf(a1, b4, acc[1][4]);
            acc[2][0] = fmaf(a2, b0, acc[2][0]); acc[2][1] = fmaf(a2, b1, acc[2][1]);
            acc[2][2] = fmaf(a2, b2, acc[2][2]); acc[2][3] = fmaf(a2, b3, acc[2][3]);
            acc[2][4] = fmaf(a2, b4, acc[2][4]);
            acc[3][0] = fmaf(a3, b0, acc[3][0]); acc[3][1] = fmaf(a3, b1, acc[3][1]);
            acc[3][2] = fmaf(a3, b2, acc[3][2]); acc[3][3] = fmaf(a3, b3, acc[3][3]);
            acc[3][4] = fmaf(a3, b4, acc[3][4]);
        }
    }
    __syncthreads();
    #pragma unroll
    for (int i = 0; i < 4; i++)
        #pragma unroll
        for (int j = 0; j < 5; j++)
            Scf[(4 * tm + i) * PS + (5 * te + j)] = acc[i][j];
    __syncthreads();

    const int w = t >> 6;
    const int l = t & 63;
    for (int it = 0; it < 8; ++it) {
        const int r = w * 8 + it;
        float s0 = Scf[r * PS + l];
        float s1 = Scf[r * PS + 64 + l];
        float s2 = (l < 32) ? Scf[r * PS + 128 + l] : -INFINITY;
        float m = fmaxf(s0, fmaxf(s1, s2));
        #pragma unroll
        for (int off = 32; off >= 1; off >>= 1) m = fmaxf(m, __shfl_xor(m, off, 64));
        float p0 = expf(s0 - m), p1 = expf(s1 - m);
        float p2 = (l < 32) ? expf(s2 - m) : 0.f;
        float sum = p0 + p1 + p2;
        #pragma unroll
        for (int off = 32; off >= 1; off >>= 1) sum += __shfl_xor(sum, off, 64);
        float inv = 1.0f / sum;
        p0 *= inv; p1 *= inv; p2 *= inv;
        const int g0 = l / GSZ, g1 = (l + 64) / GSZ, g2 = (l + 128) / GSZ;
        float gmax[NGRP];
        #pragma unroll
        for (int g = 0; g < NGRP; g++) {
            float v = -1.f;
            if (g0 == g) v = p0;
            if (g1 == g) v = fmaxf(v, p1);
            if (l < 32 && g2 == g) v = fmaxf(v, p2);
            #pragma unroll
            for (int off = 32; off >= 1; off >>= 1) v = fmaxf(v, __shfl_xor(v, off, 64));
            gmax[g] = v;
        }
        int selmask = 0;
        #pragma unroll
        for (int s = 0; s < TOPKG; s++) {
            float best = -2.f; int bg = 0;
            #pragma unroll
            for (int g = 0; g < NGRP; g++)
                if (!((selmask >> g) & 1) && gmax[g] > best) { best = gmax[g]; bg = g; }
            selmask |= 1 << bg;
        }
        float m0 = ((selmask >> g0) & 1) ? p0 : 0.f;
        float m1 = ((selmask >> g1) & 1) ? p1 : 0.f;
        float m2 = (l < 32) ? (((selmask >> g2) & 1) ? p2 : 0.f) : -1.f;
        #pragma unroll
        for (int s = 0; s < TOPK; s++) {
            float v = fmaxf(m0, fmaxf(m1, m2));
            #pragma unroll
            for (int off = 32; off >= 1; off >>= 1) v = fmaxf(v, __shfl_xor(v, off, 64));
            int idx = 0x7fffffff;
            if (m0 == v) idx = l;
            if (m1 == v) idx = min(idx, l + 64);
            if (l < 32 && m2 == v) idx = min(idx, l + 128);
            #pragma unroll
            for (int off = 32; off >= 1; off >>= 1) idx = min(idx, __shfl_xor(idx, off, 64));
            if (idx == l)            m0 = -1.f;
            else if (idx == l + 64)  m1 = -1.f;
            else if (l < 32 && idx == l + 128) m2 = -1.f;
            if (l == 0) out[(size_t)(bm0 + r) * TOPK + s] = v * RSCALE;
        }
    }
}

extern "C" void kernel_launch(void* const* d_in, const int* in_sizes, int n_in,
                              void* d_out, int out_size, void* d_ws, size_t ws_size,
                              hipStream_t stream) {
    const float* hs = (const float*)d_in[0];   // [8192][5120] fp32
    const float* kn = (const float*)d_in[1];   // [160][5120] fp32
    float* o = (float*)d_out;                  // [8192][6] fp32

    const size_t bwBytes = 2 * BW_ELEMS * sizeof(ushort);  // 3,276,800 (hi + lo)
    if (ws_size >= bwBytes) {
        ushort* Bw = (ushort*)d_ws;
        hipLaunchKernelGGL(prep_b, dim3(400), dim3(256), 0, stream, kn, Bw);
        hipLaunchKernelGGL(moe_mfma, dim3(TT / BM), dim3(512), 0, stream, hs, Bw, o);
    } else {
        hipLaunchKernelGGL(moe_gate_fused, dim3(TT / FBM), dim3(256), 0, stream, hs, kn, o);
    }
}

// Round 8
// 73.290 us; speedup vs baseline: 2.7971x; 2.0940x over previous
//
#include <hip/hip_runtime.h>
#include <math.h>

#define TT 8192
#define HH 5120
#define EE 160
#define NGRP 8
#define GSZ 20
#define TOPKG 3
#define TOPK 6
#define RSCALE 16.0f
#define SK 8              // split-K factor
#define KS (HH / SK)      // 640 K per slice
#define NSG (KS / 32)     // 20 k-steps per gemm block
#define BMG 256           // tokens per gemm block

typedef __attribute__((ext_vector_type(8))) short bf16x8;
typedef __attribute__((ext_vector_type(4))) float f32x4;

#define BW_ELEMS ((size_t)160 * 10 * 64 * 8)     // 819200 ushorts per B copy
#define BW_BYTES (BW_ELEMS * 2)                  // 1,638,400 bytes per copy

__device__ __forceinline__ ushort f2bf(float f) {
    uint32_t u = __float_as_uint(f);
    u += 0x7fff + ((u >> 16) & 1);   // RNE
    return (ushort)(u >> 16);
}
__device__ __forceinline__ float bf2f(ushort h) {
    return __uint_as_float(((uint32_t)h) << 16);
}

// ---------------- Kernel 1: B [160][5120] fp32 -> bf16 hi+lo fragment-linear ----
// layout per copy: [kt 0..159][et 0..9][lane 0..63][8 bf16]; lane&15 = expert,
// lane>>4 = k-octet -> mfma_f32_16x16x32_bf16 B-operand frag. Lo copy at +BW_ELEMS.
__global__ __launch_bounds__(256) void prep_b(const float* __restrict__ B,
                                              ushort* __restrict__ Bw) {
    int gid = blockIdx.x * 256 + threadIdx.x;        // < 102400
    int lane = gid & 63;
    int et   = (gid >> 6) % 10;
    int kt   = gid / 640;
    int e = et * 16 + (lane & 15);
    int c = kt * 32 + (lane >> 4) * 8;
    const float* src = B + (size_t)e * HH + c;
    uint4 vh, vl;
    uint32_t hw[8], lw[8];
    #pragma unroll
    for (int j = 0; j < 8; j++) {
        float f = src[j];
        ushort h = f2bf(f);
        float r = f - bf2f(h);
        hw[j] = h;
        lw[j] = f2bf(r);
    }
    vh.x = hw[0] | (hw[1] << 16); vh.y = hw[2] | (hw[3] << 16);
    vh.z = hw[4] | (hw[5] << 16); vh.w = hw[6] | (hw[7] << 16);
    vl.x = lw[0] | (lw[1] << 16); vl.y = lw[2] | (lw[3] << 16);
    vl.z = lw[4] | (lw[5] << 16); vl.w = lw[6] | (lw[7] << 16);
    *reinterpret_cast<uint4*>(Bw + (size_t)gid * 8) = vh;
    *reinterpret_cast<uint4*>(Bw + BW_ELEMS + (size_t)gid * 8) = vl;
}

__device__ __forceinline__ void split8(f32x4 x, f32x4 y, bf16x8& ah, bf16x8& al) {
    float fv[8] = {x[0], x[1], x[2], x[3], y[0], y[1], y[2], y[3]};
    union { uint32_t u[4]; bf16x8 v; } H, L;
    #pragma unroll
    for (int j = 0; j < 4; j++) {
        ushort h0 = f2bf(fv[2*j]), h1 = f2bf(fv[2*j+1]);
        float  r0 = fv[2*j]   - bf2f(h0);
        float  r1 = fv[2*j+1] - bf2f(h1);
        H.u[j] = (uint32_t)h0 | ((uint32_t)h1 << 16);
        L.u[j] = (uint32_t)f2bf(r0) | ((uint32_t)f2bf(r1) << 16);
    }
    ah = H.v; al = L.v;
}

// ---------------- Kernel 2: split-K GEMM, B shared via LDS ---------------------
// Block = 256 tokens x 640 K. 8 waves, wave w owns rows [32w, 32w+32).
// Per k-step: B tile (hi+lo, 20.5KB) staged in LDS once, read by all waves.
// Partial logits -> P[ks][token][expert] (non-atomic, block-private region).
__global__ __launch_bounds__(512, 2) void moe_gemm(const float* __restrict__ A,
                                                   const ushort* __restrict__ Bw,
                                                   float* __restrict__ P) {
    __shared__ char lds[2][20480];     // double-buffered B tile: hi 10240 | lo 10240

    const int tid = threadIdx.x;
    const int w = tid >> 6, l = tid & 63;
    const int mb  = blockIdx.x & 31;   // token-block
    const int ks  = blockIdx.x >> 5;   // k-slice
    const int bm0 = mb * BMG;
    const int kt0 = ks * NSG;          // global k-tile base

    const int row = l & 15, koct = l >> 4;

    // A pointers: this wave's two m-tiles (rows 32w+row and 32w+16+row)
    const float* apA = A + (size_t)(bm0 + 32 * w + row) * HH + ks * KS + koct * 8;
    const float* apB = apA + (size_t)16 * HH;

    // staging: 1280 16B-units per step (hi 0..639 | lo 640..1279)
    const char* BwB = (const char*)Bw;
    const int u0 = tid, u1 = tid + 512, u2 = tid + 1024;   // u2 valid if tid<256

    f32x4 acc[2][10];
    #pragma unroll
    for (int i = 0; i < 2; i++)
        #pragma unroll
        for (int et = 0; et < 10; et++) acc[i][et] = (f32x4){0.f, 0.f, 0.f, 0.f};

    // ---- prologue: stage step 0 + load A(step 0)
    uint4 r0, r1, r2;
    {
        size_t tb = (size_t)kt0 * 10240;
        r0 = *(const uint4*)(BwB + (u0 < 640 ? tb + u0 * 16 : BW_BYTES + tb + (u0 - 640) * 16));
        r1 = *(const uint4*)(BwB + BW_BYTES + tb + (size_t)(u1 - 640) * 16);  // u1 in [512,1024): lo iff >=640... handle both
        if (u1 < 640) r1 = *(const uint4*)(BwB + tb + (size_t)u1 * 16);
        if (tid < 256) r2 = *(const uint4*)(BwB + BW_BYTES + tb + (size_t)(u2 - 640) * 16);
    }
    f32x4 pa0 = *(const f32x4*)(apA), pa1 = *(const f32x4*)(apA + 4);
    f32x4 pa2 = *(const f32x4*)(apB), pa3 = *(const f32x4*)(apB + 4);
    *(uint4*)(lds[0] + u0 * 16) = r0;
    *(uint4*)(lds[0] + u1 * 16) = r1;
    if (tid < 256) *(uint4*)(lds[0] + u2 * 16) = r2;
    __syncthreads();

    #pragma unroll 1
    for (int s = 0; s < NSG; ++s) {
        const int cur = s & 1;
        const bool more = (s + 1 < NSG);
        // ---- prefetch step s+1 (B units -> regs, A -> regs); stays in flight
        uint4 n0, n1, n2;
        f32x4 na0 = pa0, na1 = pa1, na2 = pa2, na3 = pa3;
        if (more) {
            size_t tb = (size_t)(kt0 + s + 1) * 10240;
            n0 = *(const uint4*)(BwB + (u0 < 640 ? tb + u0 * 16 : BW_BYTES + tb + (u0 - 640) * 16));
            n1 = (u1 < 640) ? *(const uint4*)(BwB + tb + (size_t)u1 * 16)
                            : *(const uint4*)(BwB + BW_BYTES + tb + (size_t)(u1 - 640) * 16);
            if (tid < 256) n2 = *(const uint4*)(BwB + BW_BYTES + tb + (size_t)(u2 - 640) * 16);
            const float* a = apA + (s + 1) * 32;
            const float* b = apB + (s + 1) * 32;
            na0 = *(const f32x4*)(a); na1 = *(const f32x4*)(a + 4);
            na2 = *(const f32x4*)(b); na3 = *(const f32x4*)(b + 4);
        }

        // ---- convert current A to bf16 hi/lo fragments
        bf16x8 ah0, al0, ah1, al1;
        split8(pa0, pa1, ah0, al0);
        split8(pa2, pa3, ah1, al1);

        // ---- compute from LDS buf[cur]
        const char* LB = lds[cur];
        #pragma unroll
        for (int et = 0; et < 10; ++et) {
            bf16x8 bh = *(const bf16x8*)(LB + et * 1024 + l * 16);
            bf16x8 bl = *(const bf16x8*)(LB + 10240 + et * 1024 + l * 16);
            acc[0][et] = __builtin_amdgcn_mfma_f32_16x16x32_bf16(ah0, bh, acc[0][et], 0, 0, 0);
            acc[1][et] = __builtin_amdgcn_mfma_f32_16x16x32_bf16(ah1, bh, acc[1][et], 0, 0, 0);
            acc[0][et] = __builtin_amdgcn_mfma_f32_16x16x32_bf16(al0, bh, acc[0][et], 0, 0, 0);
            acc[1][et] = __builtin_amdgcn_mfma_f32_16x16x32_bf16(al1, bh, acc[1][et], 0, 0, 0);
            acc[0][et] = __builtin_amdgcn_mfma_f32_16x16x32_bf16(ah0, bl, acc[0][et], 0, 0, 0);
            acc[1][et] = __builtin_amdgcn_mfma_f32_16x16x32_bf16(ah1, bl, acc[1][et], 0, 0, 0);
        }
        __syncthreads();                 // all waves done reading buf[cur]
        if (more) {
            char* LN = lds[1 - cur];
            *(uint4*)(LN + u0 * 16) = n0;
            *(uint4*)(LN + u1 * 16) = n1;
            if (tid < 256) *(uint4*)(LN + u2 * 16) = n2;
        }
        pa0 = na0; pa1 = na1; pa2 = na2; pa3 = na3;
        __syncthreads();                 // buf[1-cur] ready for next step
    }

    // ---- write partial logits: P[ks][bm0 + 32w + 16i + (l>>4)*4 + j][et*16 + (l&15)]
    const int rrow = koct * 4;
    #pragma unroll
    for (int i = 0; i < 2; i++)
        #pragma unroll
        for (int et = 0; et < 10; et++)
            #pragma unroll
            for (int j = 0; j < 4; j++)
                P[((size_t)ks * TT + bm0 + 32 * w + 16 * i + rrow + j) * EE + et * 16 + row]
                    = acc[i][et][j];
}

// ---------------- Kernel 3: reduce K-slices + softmax + group-topk routing -----
__global__ __launch_bounds__(512, 4) void moe_route(const float* __restrict__ P,
                                                    float* __restrict__ out) {
    const int w = threadIdx.x >> 6, l = threadIdx.x & 63;
    const int t = blockIdx.x * 8 + w;   // token

    float s0 = 0.f, s1 = 0.f, s2 = 0.f;
    #pragma unroll
    for (int sl = 0; sl < SK; ++sl) {
        const float* b = P + ((size_t)sl * TT + t) * EE;
        s0 += b[l];
        s1 += b[64 + l];
        if (l < 32) s2 += b[128 + l];
    }
    if (l >= 32) s2 = -INFINITY;

    // ---- softmax over 160 (validated R0/R2)
    float m = fmaxf(s0, fmaxf(s1, s2));
    #pragma unroll
    for (int off = 32; off >= 1; off >>= 1) m = fmaxf(m, __shfl_xor(m, off, 64));
    float p0 = expf(s0 - m);
    float p1 = expf(s1 - m);
    float p2 = (l < 32) ? expf(s2 - m) : 0.f;
    float sum = p0 + p1 + p2;
    #pragma unroll
    for (int off = 32; off >= 1; off >>= 1) sum += __shfl_xor(sum, off, 64);
    float inv = 1.0f / sum;
    p0 *= inv; p1 *= inv; p2 *= inv;

    const int g0 = l / GSZ;
    const int g1 = (l + 64) / GSZ;
    const int g2 = (l + 128) / GSZ;

    float gmax[NGRP];
    #pragma unroll
    for (int g = 0; g < NGRP; g++) {
        float v = -1.f;
        if (g0 == g) v = p0;
        if (g1 == g) v = fmaxf(v, p1);
        if (l < 32 && g2 == g) v = fmaxf(v, p2);
        #pragma unroll
        for (int off = 32; off >= 1; off >>= 1) v = fmaxf(v, __shfl_xor(v, off, 64));
        gmax[g] = v;
    }

    int selmask = 0;
    #pragma unroll
    for (int s = 0; s < TOPKG; s++) {
        float best = -2.f; int bg = 0;
        #pragma unroll
        for (int g = 0; g < NGRP; g++)
            if (!((selmask >> g) & 1) && gmax[g] > best) { best = gmax[g]; bg = g; }
        selmask |= 1 << bg;
    }

    float m0 = ((selmask >> g0) & 1) ? p0 : 0.f;
    float m1 = ((selmask >> g1) & 1) ? p1 : 0.f;
    float m2 = (l < 32) ? (((selmask >> g2) & 1) ? p2 : 0.f) : -1.f;

    #pragma unroll
    for (int s = 0; s < TOPK; s++) {
        float v = fmaxf(m0, fmaxf(m1, m2));
        #pragma unroll
        for (int off = 32; off >= 1; off >>= 1) v = fmaxf(v, __shfl_xor(v, off, 64));
        int idx = 0x7fffffff;
        if (m0 == v) idx = l;
        if (m1 == v) idx = min(idx, l + 64);
        if (l < 32 && m2 == v) idx = min(idx, l + 128);
        #pragma unroll
        for (int off = 32; off >= 1; off >>= 1) idx = min(idx, __shfl_xor(idx, off, 64));
        if (idx == l)            m0 = -1.f;
        else if (idx == l + 64)  m1 = -1.f;
        else if (l < 32 && idx == l + 128) m2 = -1.f;
        if (l == 0) out[(size_t)t * TOPK + s] = v * RSCALE;
    }
}

// ---------------- Mid-tier fallback: R6 kernel (ws too small for partials) -----
#define BM 16
#define KW 640
#define NS (KW / 32)
#define PS (EE + 1)

__global__ __launch_bounds__(512, 4) void moe_mfma(const float* __restrict__ A,
                                                   const ushort* __restrict__ Bw,
                                                   float* __restrict__ out) {
    __shared__ float Sc[BM * PS];

    const int tid = threadIdx.x;
    const int w = tid >> 6, l = tid & 63;
    const int bm0 = blockIdx.x * BM;
    const int row  = l & 15;
    const int koct = l >> 4;

    f32x4 acc[10];
    #pragma unroll
    for (int et = 0; et < 10; et++) acc[et] = (f32x4){0.f, 0.f, 0.f, 0.f};

    const float* apw = A + (size_t)(bm0 + row) * HH + w * KW + koct * 8;

    #pragma unroll 1
    for (int s = 0; s < NS; ++s) {
        const f32x4* p = (const f32x4*)(apw + s * 32);
        bf16x8 ah, al;
        split8(p[0], p[1], ah, al);
        const ushort* bt = Bw + ((size_t)((w * NS + s) * 10) * 64 + (size_t)l) * 8;
        #pragma unroll
        for (int et = 0; et < 10; ++et) {
            bf16x8 bh = *(const bf16x8*)(bt + et * 512);
            bf16x8 bl = *(const bf16x8*)(bt + BW_ELEMS + et * 512);
            acc[et] = __builtin_amdgcn_mfma_f32_16x16x32_bf16(ah, bh, acc[et], 0, 0, 0);
            acc[et] = __builtin_amdgcn_mfma_f32_16x16x32_bf16(al, bh, acc[et], 0, 0, 0);
            acc[et] = __builtin_amdgcn_mfma_f32_16x16x32_bf16(ah, bl, acc[et], 0, 0, 0);
        }
    }

    for (int i = tid; i < BM * PS; i += 512) Sc[i] = 0.f;
    __syncthreads();
    const int rrow = koct * 4;
    #pragma unroll
    for (int et = 0; et < 10; et++)
        #pragma unroll
        for (int j = 0; j < 4; j++)
            atomicAdd(&Sc[(rrow + j) * PS + et * 16 + row], acc[et][j]);
    __syncthreads();

    for (int it = 0; it < 2; ++it) {
        const int r = w * 2 + it;
        float s0 = Sc[r * PS + l];
        float s1 = Sc[r * PS + 64 + l];
        float s2 = (l < 32) ? Sc[r * PS + 128 + l] : -INFINITY;

        float m = fmaxf(s0, fmaxf(s1, s2));
        #pragma unroll
        for (int off = 32; off >= 1; off >>= 1) m = fmaxf(m, __shfl_xor(m, off, 64));
        float p0 = expf(s0 - m);
        float p1 = expf(s1 - m);
        float p2 = (l < 32) ? expf(s2 - m) : 0.f;
        float sum = p0 + p1 + p2;
        #pragma unroll
        for (int off = 32; off >= 1; off >>= 1) sum += __shfl_xor(sum, off, 64);
        float inv = 1.0f / sum;
        p0 *= inv; p1 *= inv; p2 *= inv;

        const int g0 = l / GSZ;
        const int g1 = (l + 64) / GSZ;
        const int g2 = (l + 128) / GSZ;

        float gmax[NGRP];
        #pragma unroll
        for (int g = 0; g < NGRP; g++) {
            float v = -1.f;
            if (g0 == g) v = p0;
            if (g1 == g) v = fmaxf(v, p1);
            if (l < 32 && g2 == g) v = fmaxf(v, p2);
            #pragma unroll
            for (int off = 32; off >= 1; off >>= 1) v = fmaxf(v, __shfl_xor(v, off, 64));
            gmax[g] = v;
        }

        int selmask = 0;
        #pragma unroll
        for (int s = 0; s < TOPKG; s++) {
            float best = -2.f; int bg = 0;
            #pragma unroll
            for (int g = 0; g < NGRP; g++)
                if (!((selmask >> g) & 1) && gmax[g] > best) { best = gmax[g]; bg = g; }
            selmask |= 1 << bg;
        }

        float m0 = ((selmask >> g0) & 1) ? p0 : 0.f;
        float m1 = ((selmask >> g1) & 1) ? p1 : 0.f;
        float m2 = (l < 32) ? (((selmask >> g2) & 1) ? p2 : 0.f) : -1.f;

        #pragma unroll
        for (int s = 0; s < TOPK; s++) {
            float v = fmaxf(m0, fmaxf(m1, m2));
            #pragma unroll
            for (int off = 32; off >= 1; off >>= 1) v = fmaxf(v, __shfl_xor(v, off, 64));
            int idx = 0x7fffffff;
            if (m0 == v) idx = l;
            if (m1 == v) idx = min(idx, l + 64);
            if (l < 32 && m2 == v) idx = min(idx, l + 128);
            #pragma unroll
            for (int off = 32; off >= 1; off >>= 1) idx = min(idx, __shfl_xor(idx, off, 64));
            if (idx == l)            m0 = -1.f;
            else if (idx == l + 64)  m1 = -1.f;
            else if (l < 32 && idx == l + 128) m2 = -1.f;
            if (l == 0) out[(size_t)(bm0 + r) * TOPK + s] = v * RSCALE;
        }
    }
}

extern "C" void kernel_launch(void* const* d_in, const int* in_sizes, int n_in,
                              void* d_out, int out_size, void* d_ws, size_t ws_size,
                              hipStream_t stream) {
    const float* hs = (const float*)d_in[0];   // [8192][5120] fp32
    const float* kn = (const float*)d_in[1];   // [160][5120] fp32
    float* o = (float*)d_out;                  // [8192][6] fp32

    const size_t bwBytes = 2 * BW_BYTES;                     // 3,276,800
    const size_t pBytes  = (size_t)SK * TT * EE * 4;         // 41,943,040
    if (ws_size >= bwBytes + pBytes) {
        ushort* Bw = (ushort*)d_ws;
        float*  P  = (float*)((char*)d_ws + bwBytes);
        hipLaunchKernelGGL(prep_b,   dim3(400),      dim3(256), 0, stream, kn, Bw);
        hipLaunchKernelGGL(moe_gemm, dim3(32 * SK),  dim3(512), 0, stream, hs, Bw, P);
        hipLaunchKernelGGL(moe_route,dim3(TT / 8),   dim3(512), 0, stream, P, o);
    } else {
        ushort* Bw = (ushort*)d_ws;
        hipLaunchKernelGGL(prep_b,   dim3(400),      dim3(256), 0, stream, kn, Bw);
        hipLaunchKernelGGL(moe_mfma, dim3(TT / BM),  dim3(512), 0, stream, hs, Bw, o);
    }
}

// Round 9
// 63.191 us; speedup vs baseline: 3.2441x; 1.1598x over previous
//
#include <hip/hip_runtime.h>
#include <math.h>

#define TT 8192
#define HH 5120
#define EE 160
#define NGRP 8
#define GSZ 20
#define TOPKG 3
#define TOPK 6
#define RSCALE 16.0f
#define SK 8              // split-K factor
#define KS (HH / SK)      // 640 K per slice
#define NSG (KS / 32)     // 20 k-steps per gemm block
#define BMG 256           // tokens per gemm block

typedef __attribute__((ext_vector_type(8))) short bf16x8;
typedef __attribute__((ext_vector_type(8))) _Float16 f16x8;
typedef __attribute__((ext_vector_type(4))) float f32x4;

#define BW_ELEMS ((size_t)160 * 10 * 64 * 8)     // 819200 frag elements per copy
#define BWH_BYTES (BW_ELEMS * 2)                 // 1,638,400 bytes (f16 single copy)

__device__ __forceinline__ ushort f2bf(float f) {
    uint32_t u = __float_as_uint(f);
    u += 0x7fff + ((u >> 16) & 1);   // RNE
    return (ushort)(u >> 16);
}
__device__ __forceinline__ float bf2f(ushort h) {
    return __uint_as_float(((uint32_t)h) << 16);
}

// pack 8 fp32 -> 8 f16 (RNE via _Float16 cast; v_cvt_f16_f32 is RNE)
__device__ __forceinline__ f16x8 cvt8(f32x4 x, f32x4 y) {
    f16x8 r;
    r[0] = (_Float16)x[0]; r[1] = (_Float16)x[1];
    r[2] = (_Float16)x[2]; r[3] = (_Float16)x[3];
    r[4] = (_Float16)y[0]; r[5] = (_Float16)y[1];
    r[6] = (_Float16)y[2]; r[7] = (_Float16)y[3];
    return r;
}

// ---------------- Kernel 1: B [160][5120] fp32 -> f16 fragment-linear ----------
// layout: [kt 0..159][et 0..9][lane 0..63][8 f16]; lane&15 = expert,
// lane>>4 = k-octet -> mfma_f32_16x16x32_f16 B-operand frag.
__global__ __launch_bounds__(256) void prep_b_f16(const float* __restrict__ B,
                                                  ushort* __restrict__ Bw) {
    int gid = blockIdx.x * 256 + threadIdx.x;        // < 102400
    int lane = gid & 63;
    int et   = (gid >> 6) % 10;
    int kt   = gid / 640;
    int e = et * 16 + (lane & 15);
    int c = kt * 32 + (lane >> 4) * 8;
    const float* src = B + (size_t)e * HH + c;
    f32x4 s0 = *(const f32x4*)src;
    f32x4 s1 = *(const f32x4*)(src + 4);
    union { f16x8 h; uint4 v; } u;
    u.h = cvt8(s0, s1);
    *reinterpret_cast<uint4*>(Bw + (size_t)gid * 8) = u.v;
}

// ---------------- Kernel 2: split-K GEMM (f16 single pass), B shared via LDS ---
// Block = 256 tokens x 640 K. 8 waves, wave w owns rows [32w, 32w+32).
// Per k-step: B tile (10.25KB f16) staged in LDS once, read by all waves.
// Partial logits -> P[ks][token][expert] (non-atomic, block-private region).
__global__ __launch_bounds__(512, 2) void moe_gemm(const float* __restrict__ A,
                                                   const ushort* __restrict__ Bw,
                                                   float* __restrict__ P) {
    __shared__ char lds[2][10240];     // double-buffered B tile (f16)

    const int tid = threadIdx.x;
    const int w = tid >> 6, l = tid & 63;
    const int mb  = blockIdx.x & 31;   // token-block
    const int ks  = blockIdx.x >> 5;   // k-slice
    const int bm0 = mb * BMG;
    const int kt0 = ks * NSG;          // global k-tile base

    const int row = l & 15, koct = l >> 4;

    // A pointers: this wave's two m-tiles (rows 32w+row and 32w+16+row)
    const float* apA = A + (size_t)(bm0 + 32 * w + row) * HH + ks * KS + koct * 8;
    const float* apB = apA + (size_t)16 * HH;

    // staging: 640 16B-units per step; u0 for all 512 threads, u1 for tid<128
    const char* BwB = (const char*)Bw;
    const int u0 = tid, u1 = tid + 512;

    f32x4 acc[2][10];
    #pragma unroll
    for (int i = 0; i < 2; i++)
        #pragma unroll
        for (int et = 0; et < 10; et++) acc[i][et] = (f32x4){0.f, 0.f, 0.f, 0.f};

    // ---- prologue: stage step 0 + load A(step 0)
    uint4 r0, r1;
    {
        size_t tb = (size_t)kt0 * 10240;
        r0 = *(const uint4*)(BwB + tb + (size_t)u0 * 16);
        if (tid < 128) r1 = *(const uint4*)(BwB + tb + (size_t)u1 * 16);
    }
    f32x4 pa0 = *(const f32x4*)(apA), pa1 = *(const f32x4*)(apA + 4);
    f32x4 pa2 = *(const f32x4*)(apB), pa3 = *(const f32x4*)(apB + 4);
    *(uint4*)(lds[0] + u0 * 16) = r0;
    if (tid < 128) *(uint4*)(lds[0] + u1 * 16) = r1;
    __syncthreads();

    #pragma unroll 1
    for (int s = 0; s < NSG; ++s) {
        const int cur = s & 1;
        const bool more = (s + 1 < NSG);
        // ---- prefetch step s+1 (B units -> regs, A -> regs); stays in flight
        uint4 n0, n1;
        f32x4 na0 = pa0, na1 = pa1, na2 = pa2, na3 = pa3;
        if (more) {
            size_t tb = (size_t)(kt0 + s + 1) * 10240;
            n0 = *(const uint4*)(BwB + tb + (size_t)u0 * 16);
            if (tid < 128) n1 = *(const uint4*)(BwB + tb + (size_t)u1 * 16);
            const float* a = apA + (s + 1) * 32;
            const float* b = apB + (s + 1) * 32;
            na0 = *(const f32x4*)(a); na1 = *(const f32x4*)(a + 4);
            na2 = *(const f32x4*)(b); na3 = *(const f32x4*)(b + 4);
        }

        // ---- convert current A to f16 fragments (single pass)
        f16x8 ah0 = cvt8(pa0, pa1);
        f16x8 ah1 = cvt8(pa2, pa3);

        // ---- compute from LDS buf[cur]: 10 B reads, 20 MFMAs per wave
        const char* LB = lds[cur];
        #pragma unroll
        for (int et = 0; et < 10; ++et) {
            f16x8 bh = *(const f16x8*)(LB + et * 1024 + l * 16);
            acc[0][et] = __builtin_amdgcn_mfma_f32_16x16x32_f16(ah0, bh, acc[0][et], 0, 0, 0);
            acc[1][et] = __builtin_amdgcn_mfma_f32_16x16x32_f16(ah1, bh, acc[1][et], 0, 0, 0);
        }
        __syncthreads();                 // all waves done reading buf[cur]
        if (more) {
            char* LN = lds[1 - cur];
            *(uint4*)(LN + u0 * 16) = n0;
            if (tid < 128) *(uint4*)(LN + u1 * 16) = n1;
        }
        pa0 = na0; pa1 = na1; pa2 = na2; pa3 = na3;
        __syncthreads();                 // buf[1-cur] ready for next step
    }

    // ---- write partial logits: P[ks][bm0 + 32w + 16i + (l>>4)*4 + j][et*16 + (l&15)]
    const int rrow = koct * 4;
    #pragma unroll
    for (int i = 0; i < 2; i++)
        #pragma unroll
        for (int et = 0; et < 10; et++)
            #pragma unroll
            for (int j = 0; j < 4; j++)
                P[((size_t)ks * TT + bm0 + 32 * w + 16 * i + rrow + j) * EE + et * 16 + row]
                    = acc[i][et][j];
}

// ---------------- Kernel 3: reduce K-slices + softmax + group-topk routing -----
__global__ __launch_bounds__(512, 4) void moe_route(const float* __restrict__ P,
                                                    float* __restrict__ out) {
    const int w = threadIdx.x >> 6, l = threadIdx.x & 63;
    const int t = blockIdx.x * 8 + w;   // token

    float s0 = 0.f, s1 = 0.f, s2 = 0.f;
    #pragma unroll
    for (int sl = 0; sl < SK; ++sl) {
        const float* b = P + ((size_t)sl * TT + t) * EE;
        s0 += b[l];
        s1 += b[64 + l];
        if (l < 32) s2 += b[128 + l];
    }
    if (l >= 32) s2 = -INFINITY;

    // ---- softmax over 160 (validated R0/R2)
    float m = fmaxf(s0, fmaxf(s1, s2));
    #pragma unroll
    for (int off = 32; off >= 1; off >>= 1) m = fmaxf(m, __shfl_xor(m, off, 64));
    float p0 = expf(s0 - m);
    float p1 = expf(s1 - m);
    float p2 = (l < 32) ? expf(s2 - m) : 0.f;
    float sum = p0 + p1 + p2;
    #pragma unroll
    for (int off = 32; off >= 1; off >>= 1) sum += __shfl_xor(sum, off, 64);
    float inv = 1.0f / sum;
    p0 *= inv; p1 *= inv; p2 *= inv;

    const int g0 = l / GSZ;
    const int g1 = (l + 64) / GSZ;
    const int g2 = (l + 128) / GSZ;

    float gmax[NGRP];
    #pragma unroll
    for (int g = 0; g < NGRP; g++) {
        float v = -1.f;
        if (g0 == g) v = p0;
        if (g1 == g) v = fmaxf(v, p1);
        if (l < 32 && g2 == g) v = fmaxf(v, p2);
        #pragma unroll
        for (int off = 32; off >= 1; off >>= 1) v = fmaxf(v, __shfl_xor(v, off, 64));
        gmax[g] = v;
    }

    int selmask = 0;
    #pragma unroll
    for (int s = 0; s < TOPKG; s++) {
        float best = -2.f; int bg = 0;
        #pragma unroll
        for (int g = 0; g < NGRP; g++)
            if (!((selmask >> g) & 1) && gmax[g] > best) { best = gmax[g]; bg = g; }
        selmask |= 1 << bg;
    }

    float m0 = ((selmask >> g0) & 1) ? p0 : 0.f;
    float m1 = ((selmask >> g1) & 1) ? p1 : 0.f;
    float m2 = (l < 32) ? (((selmask >> g2) & 1) ? p2 : 0.f) : -1.f;

    #pragma unroll
    for (int s = 0; s < TOPK; s++) {
        float v = fmaxf(m0, fmaxf(m1, m2));
        #pragma unroll
        for (int off = 32; off >= 1; off >>= 1) v = fmaxf(v, __shfl_xor(v, off, 64));
        int idx = 0x7fffffff;
        if (m0 == v) idx = l;
        if (m1 == v) idx = min(idx, l + 64);
        if (l < 32 && m2 == v) idx = min(idx, l + 128);
        #pragma unroll
        for (int off = 32; off >= 1; off >>= 1) idx = min(idx, __shfl_xor(idx, off, 64));
        if (idx == l)            m0 = -1.f;
        else if (idx == l + 64)  m1 = -1.f;
        else if (l < 32 && idx == l + 128) m2 = -1.f;
        if (l == 0) out[(size_t)t * TOPK + s] = v * RSCALE;
    }
}

// ---------------- Fallback tier: R6 bf16 3-pass (ws too small for partials) ----
#define BM 16
#define KW 640
#define NS (KW / 32)
#define PS (EE + 1)

__global__ __launch_bounds__(256) void prep_b_bf16(const float* __restrict__ B,
                                                   ushort* __restrict__ Bw) {
    int gid = blockIdx.x * 256 + threadIdx.x;
    int lane = gid & 63;
    int et   = (gid >> 6) % 10;
    int kt   = gid / 640;
    int e = et * 16 + (lane & 15);
    int c = kt * 32 + (lane >> 4) * 8;
    const float* src = B + (size_t)e * HH + c;
    uint4 vh, vl;
    uint32_t hw[8], lw[8];
    #pragma unroll
    for (int j = 0; j < 8; j++) {
        float f = src[j];
        ushort h = f2bf(f);
        float r = f - bf2f(h);
        hw[j] = h;
        lw[j] = f2bf(r);
    }
    vh.x = hw[0] | (hw[1] << 16); vh.y = hw[2] | (hw[3] << 16);
    vh.z = hw[4] | (hw[5] << 16); vh.w = hw[6] | (hw[7] << 16);
    vl.x = lw[0] | (lw[1] << 16); vl.y = lw[2] | (lw[3] << 16);
    vl.z = lw[4] | (lw[5] << 16); vl.w = lw[6] | (lw[7] << 16);
    *reinterpret_cast<uint4*>(Bw + (size_t)gid * 8) = vh;
    *reinterpret_cast<uint4*>(Bw + BW_ELEMS + (size_t)gid * 8) = vl;
}

__device__ __forceinline__ void split8(f32x4 x, f32x4 y, bf16x8& ah, bf16x8& al) {
    float fv[8] = {x[0], x[1], x[2], x[3], y[0], y[1], y[2], y[3]};
    union { uint32_t u[4]; bf16x8 v; } H, L;
    #pragma unroll
    for (int j = 0; j < 4; j++) {
        ushort h0 = f2bf(fv[2*j]), h1 = f2bf(fv[2*j+1]);
        float  r0 = fv[2*j]   - bf2f(h0);
        float  r1 = fv[2*j+1] - bf2f(h1);
        H.u[j] = (uint32_t)h0 | ((uint32_t)h1 << 16);
        L.u[j] = (uint32_t)f2bf(r0) | ((uint32_t)f2bf(r1) << 16);
    }
    ah = H.v; al = L.v;
}

__global__ __launch_bounds__(512, 4) void moe_mfma(const float* __restrict__ A,
                                                   const ushort* __restrict__ Bw,
                                                   float* __restrict__ out) {
    __shared__ float Sc[BM * PS];

    const int tid = threadIdx.x;
    const int w = tid >> 6, l = tid & 63;
    const int bm0 = blockIdx.x * BM;
    const int row  = l & 15;
    const int koct = l >> 4;

    f32x4 acc[10];
    #pragma unroll
    for (int et = 0; et < 10; et++) acc[et] = (f32x4){0.f, 0.f, 0.f, 0.f};

    const float* apw = A + (size_t)(bm0 + row) * HH + w * KW + koct * 8;

    #pragma unroll 1
    for (int s = 0; s < NS; ++s) {
        const f32x4* p = (const f32x4*)(apw + s * 32);
        bf16x8 ah, al;
        split8(p[0], p[1], ah, al);
        const ushort* bt = Bw + ((size_t)((w * NS + s) * 10) * 64 + (size_t)l) * 8;
        #pragma unroll
        for (int et = 0; et < 10; ++et) {
            bf16x8 bh = *(const bf16x8*)(bt + et * 512);
            bf16x8 bl = *(const bf16x8*)(bt + BW_ELEMS + et * 512);
            acc[et] = __builtin_amdgcn_mfma_f32_16x16x32_bf16(ah, bh, acc[et], 0, 0, 0);
            acc[et] = __builtin_amdgcn_mfma_f32_16x16x32_bf16(al, bh, acc[et], 0, 0, 0);
            acc[et] = __builtin_amdgcn_mfma_f32_16x16x32_bf16(ah, bl, acc[et], 0, 0, 0);
        }
    }

    for (int i = tid; i < BM * PS; i += 512) Sc[i] = 0.f;
    __syncthreads();
    const int rrow = koct * 4;
    #pragma unroll
    for (int et = 0; et < 10; et++)
        #pragma unroll
        for (int j = 0; j < 4; j++)
            atomicAdd(&Sc[(rrow + j) * PS + et * 16 + row], acc[et][j]);
    __syncthreads();

    for (int it = 0; it < 2; ++it) {
        const int r = w * 2 + it;
        float s0 = Sc[r * PS + l];
        float s1 = Sc[r * PS + 64 + l];
        float s2 = (l < 32) ? Sc[r * PS + 128 + l] : -INFINITY;

        float m = fmaxf(s0, fmaxf(s1, s2));
        #pragma unroll
        for (int off = 32; off >= 1; off >>= 1) m = fmaxf(m, __shfl_xor(m, off, 64));
        float p0 = expf(s0 - m);
        float p1 = expf(s1 - m);
        float p2 = (l < 32) ? expf(s2 - m) : 0.f;
        float sum = p0 + p1 + p2;
        #pragma unroll
        for (int off = 32; off >= 1; off >>= 1) sum += __shfl_xor(sum, off, 64);
        float inv = 1.0f / sum;
        p0 *= inv; p1 *= inv; p2 *= inv;

        const int g0 = l / GSZ;
        const int g1 = (l + 64) / GSZ;
        const int g2 = (l + 128) / GSZ;

        float gmax[NGRP];
        #pragma unroll
        for (int g = 0; g < NGRP; g++) {
            float v = -1.f;
            if (g0 == g) v = p0;
            if (g1 == g) v = fmaxf(v, p1);
            if (l < 32 && g2 == g) v = fmaxf(v, p2);
            #pragma unroll
            for (int off = 32; off >= 1; off >>= 1) v = fmaxf(v, __shfl_xor(v, off, 64));
            gmax[g] = v;
        }

        int selmask = 0;
        #pragma unroll
        for (int s = 0; s < TOPKG; s++) {
            float best = -2.f; int bg = 0;
            #pragma unroll
            for (int g = 0; g < NGRP; g++)
                if (!((selmask >> g) & 1) && gmax[g] > best) { best = gmax[g]; bg = g; }
            selmask |= 1 << bg;
        }

        float m0 = ((selmask >> g0) & 1) ? p0 : 0.f;
        float m1 = ((selmask >> g1) & 1) ? p1 : 0.f;
        float m2 = (l < 32) ? (((selmask >> g2) & 1) ? p2 : 0.f) : -1.f;

        #pragma unroll
        for (int s = 0; s < TOPK; s++) {
            float v = fmaxf(m0, fmaxf(m1, m2));
            #pragma unroll
            for (int off = 32; off >= 1; off >>= 1) v = fmaxf(v, __shfl_xor(v, off, 64));
            int idx = 0x7fffffff;
            if (m0 == v) idx = l;
            if (m1 == v) idx = min(idx, l + 64);
            if (l < 32 && m2 == v) idx = min(idx, l + 128);
            #pragma unroll
            for (int off = 32; off >= 1; off >>= 1) idx = min(idx, __shfl_xor(idx, off, 64));
            if (idx == l)            m0 = -1.f;
            else if (idx == l + 64)  m1 = -1.f;
            else if (l < 32 && idx == l + 128) m2 = -1.f;
            if (l == 0) out[(size_t)(bm0 + r) * TOPK + s] = v * RSCALE;
        }
    }
}

extern "C" void kernel_launch(void* const* d_in, const int* in_sizes, int n_in,
                              void* d_out, int out_size, void* d_ws, size_t ws_size,
                              hipStream_t stream) {
    const float* hs = (const float*)d_in[0];   // [8192][5120] fp32
    const float* kn = (const float*)d_in[1];   // [160][5120] fp32
    float* o = (float*)d_out;                  // [8192][6] fp32

    const size_t pBytes = (size_t)SK * TT * EE * 4;          // 41,943,040
    if (ws_size >= BWH_BYTES + pBytes) {
        ushort* Bw = (ushort*)d_ws;
        float*  P  = (float*)((char*)d_ws + BWH_BYTES);
        hipLaunchKernelGGL(prep_b_f16, dim3(400),     dim3(256), 0, stream, kn, Bw);
        hipLaunchKernelGGL(moe_gemm,   dim3(32 * SK), dim3(512), 0, stream, hs, Bw, P);
        hipLaunchKernelGGL(moe_route,  dim3(TT / 8),  dim3(512), 0, stream, P, o);
    } else {
        ushort* Bw = (ushort*)d_ws;
        hipLaunchKernelGGL(prep_b_bf16, dim3(400),    dim3(256), 0, stream, kn, Bw);
        hipLaunchKernelGGL(moe_mfma,   dim3(TT / BM), dim3(512), 0, stream, hs, Bw, o);
    }
}